// Round 19
// baseline (130.258 us; speedup 1.0000x reference)
//
#include <hip/hip_runtime.h>

#define NN 50000
#define NE 800000
#define D 128
#define SEGBITS 8
#define SEGSZ 256
#define NSEG 196         // ceil(50000/256)
#define GRID_A 1024
#define EPB ((NE + GRID_A - 1) / GRID_A)   // 782
#define FLAT (NSEG * GRID_A)               // 200704

typedef __attribute__((ext_vector_type(8))) short short8;
typedef __attribute__((ext_vector_type(4))) float f32x4;
typedef __attribute__((ext_vector_type(2))) float f32x2;

__device__ inline unsigned short f2bf(float f) {
    unsigned u = __builtin_bit_cast(unsigned, f);
    unsigned r = (u + 0x7fffu + ((u >> 16) & 1u)) >> 16;
    return (unsigned short)r;
}
__device__ inline float bflo(unsigned u) { return __builtin_bit_cast(float, u << 16); }
__device__ inline float bfhi(unsigned u) { return __builtin_bit_cast(float, u & 0xffff0000u); }

// ---- fp8 e4m3 encode/decode (hardware cvt on gfx950; software fallback) ----
#if __has_builtin(__builtin_amdgcn_cvt_pk_f32_fp8) && __has_builtin(__builtin_amdgcn_cvt_pk_fp8_f32)
#define HW_FP8 1
#endif

__device__ inline unsigned char f2fp8(float f) {
#ifdef HW_FP8
    int r = __builtin_amdgcn_cvt_pk_fp8_f32(f, f, 0, false);
    return (unsigned char)(r & 0xff);
#else
    float a = fabsf(f);
    unsigned s = (__builtin_bit_cast(unsigned, f) >> 31) << 7;
    a = fminf(a, 448.f);
    if (a < 0.015625f) {                       // subnormal: m * 2^-9
        unsigned m = (unsigned)(a * 512.f + 0.5f);
        return (unsigned char)(s | m);
    }
    unsigned u = __builtin_bit_cast(unsigned, a);
    u += 0x0FFFFF + ((u >> 20) & 1);           // RTN-even to 3 mantissa bits
    int e8 = (int)(u >> 23) - 127 + 7;
    unsigned m = (u >> 20) & 7;
    unsigned code = (unsigned)(e8 << 3) | m;
    if (code > 0x7E) code = 0x7E;              // saturate to 448
    return (unsigned char)(s | code);
#endif
}

#ifndef HW_FP8
__device__ inline float fp8_to_f32(unsigned char c) {
    unsigned s = (c >> 7) & 1u, e = (c >> 3) & 15u, m = c & 7u;
    float v = (e == 0) ? (float)m * 0.001953125f
                       : __builtin_bit_cast(float, ((e + 120u) << 23) | (m << 20));
    return s ? -v : v;
}
#endif

// ---------------- CSR build: atomic-free two-level counting sort ----------------

// A1: per-block coarse histogram (196 segments); blocks 0..31 also frag-pack W
__global__ __launch_bounds__(256) void histA_kernel(const int* __restrict__ dst,
        int* __restrict__ bh,
        const float* __restrict__ W0, const float* __restrict__ W1,
        const float* __restrict__ W2, const float* __restrict__ W3,
        unsigned short* __restrict__ wf) {
    __shared__ int h[NSEG];
    int t = threadIdx.x;
    int b = blockIdx.x;
    if (t < NSEG) h[t] = 0;
    __syncthreads();
    int beg = b * EPB;
    int end = min(beg + EPB, NE);
    for (int e = beg + t; e < end; e += 256) atomicAdd(&h[dst[e] >> SEGBITS], 1);
    __syncthreads();
    if (t < NSEG) bh[t * GRID_A + b] = h[t];
    if (b < 32) {   // prep_w: frag f=ct*4+kk, lane l: col=ct*16+(l&15), k=kk*32+(l>>4)*8+e
        int tg = b * 256 + t;
        int w = tg >> 11, rem = tg & 2047;
        int f = rem >> 6, l = rem & 63;
        int ct = f >> 2, kk = f & 3;
        int col = ct * 16 + (l & 15);
        int k0 = kk * 32 + (l >> 4) * 8;
        const float* W = (w == 0) ? W0 : (w == 1) ? W1 : (w == 2) ? W2 : W3;
        unsigned short* o = wf + (size_t)w * 16384 + ((size_t)f * 64 + l) * 8;
        #pragma unroll
        for (int e = 0; e < 8; ++e) o[e] = f2bf(W[(k0 + e) * D + col]);
    }
}

// A2a: per-segment scan of its 1024 per-block counts -> bases + segment total
__global__ __launch_bounds__(256) void segscan_kernel(const int* __restrict__ bh,
        int* __restrict__ bases, int* __restrict__ segTot) {
    __shared__ int s[256];
    int sg = blockIdx.x, t = threadIdx.x;
    const int* p = bh + (size_t)sg * GRID_A;
    int v0 = p[t * 4], v1 = p[t * 4 + 1], v2 = p[t * 4 + 2], v3 = p[t * 4 + 3];
    int sum = v0 + v1 + v2 + v3;
    s[t] = sum;
    __syncthreads();
    #pragma unroll
    for (int off = 1; off < 256; off <<= 1) {
        int u = (t >= off) ? s[t - off] : 0;
        __syncthreads();
        s[t] += u;
        __syncthreads();
    }
    int run = s[t] - sum;
    int* q = bases + (size_t)sg * GRID_A;
    q[t * 4] = run; run += v0;
    q[t * 4 + 1] = run; run += v1;
    q[t * 4 + 2] = run; run += v2;
    q[t * 4 + 3] = run;
    if (t == 255) segTot[sg] = s[255];
}

// A2b: exclusive scan of 196 segment totals -> segBase
__global__ __launch_bounds__(256) void segbase_kernel(const int* __restrict__ segTot,
        int* __restrict__ segBase) {
    __shared__ int s[256];
    int t = threadIdx.x;
    int v = (t < NSEG) ? segTot[t] : 0;
    s[t] = v;
    __syncthreads();
    #pragma unroll
    for (int off = 1; off < 256; off <<= 1) {
        int u = (t >= off) ? s[t - off] : 0;
        __syncthreads();
        s[t] += u;
        __syncthreads();
    }
    if (t < NSEG) segBase[t] = s[t] - v;
    if (t == 0) segBase[NSEG] = NE;
}

// A3: scatter edges into segment buckets, packed (dst_local<<24 | src)
__global__ __launch_bounds__(256) void scatA_kernel(const int* __restrict__ src,
        const int* __restrict__ dst, const int* __restrict__ bases,
        const int* __restrict__ segBase, unsigned* __restrict__ bucket) {
    __shared__ int cur[NSEG];
    int t = threadIdx.x;
    if (t < NSEG) cur[t] = segBase[t] + bases[t * GRID_A + blockIdx.x];
    __syncthreads();
    int beg = blockIdx.x * EPB;
    int end = min(beg + EPB, NE);
    for (int e = beg + t; e < end; e += 256) {
        int d = dst[e];
        int sg = d >> SEGBITS;
        int p = atomicAdd(&cur[sg], 1);          // LDS atomic
        bucket[p] = ((unsigned)(d & (SEGSZ - 1)) << 24) | (unsigned)src[e];
    }
}

// B: per-segment fine histogram (1 bin/thread) + in-LDS scan -> rowptr + csr
__global__ __launch_bounds__(256) void buildB_kernel(const unsigned* __restrict__ bucket,
        const int* __restrict__ segBase, int* __restrict__ rowptr, int* __restrict__ csr) {
    __shared__ int h[SEGSZ];    // 1 KB, bin t owned by thread t
    __shared__ int s[SEGSZ];
    int sg = blockIdx.x;
    int t = threadIdx.x;
    int beg = segBase[sg], end = segBase[sg + 1];
    h[t] = 0;
    __syncthreads();
    for (int i = beg + t; i < end; i += 256) atomicAdd(&h[bucket[i] >> 24], 1);  // LDS
    __syncthreads();
    int v = h[t];
    s[t] = v;
    __syncthreads();
    #pragma unroll
    for (int off = 1; off < 256; off <<= 1) {
        int u = (t >= off) ? s[t - off] : 0;
        __syncthreads();
        s[t] += u;
        __syncthreads();
    }
    int excl = beg + s[t] - v;
    int n = sg * SEGSZ + t;
    if (n <= NN) rowptr[n] = excl;      // covers rowptr[NN] = NE (node 50000 -> sg 195, t 80)
    h[t] = excl;                        // becomes placement cursor
    __syncthreads();
    for (int i = beg + t; i < end; i += 256) {
        unsigned u = bucket[i];
        int p = atomicAdd(&h[u >> 24], 1);       // LDS
        csr[p] = (int)(u & 0xFFFFFFu);
    }
}

// ---------------- dual-output bf16 MFMA GEMM: Y(fp8) = A@Wl, Z(bf16) = A@Wr ----
// LDS-staged W (64 KB) amortizes W-frag L2 latency (R10 vs R11: 132.6 vs 138.6).
// launch_bounds (256,2): 2 blocks/CU (2x64KB LDS fits in 160KB).
// AFP32: A is fp32 row-major (converted to bf16 frags in-register)

template<int AFP32>
__global__ __launch_bounds__(256, 2) void gemm_kernel(const void* __restrict__ Av,
        const unsigned short* __restrict__ WfL, const unsigned short* __restrict__ WfR,
        unsigned char* __restrict__ Yf, unsigned short* __restrict__ Zb, int nrows) {
    __shared__ short8 sW[4096];   // Wl frags | Wr frags (64 KB)

    for (int i = threadIdx.x; i < 2048; i += 256) {
        sW[i]        = ((const short8*)WfL)[i];
        sW[i + 2048] = ((const short8*)WfR)[i];
    }
    __syncthreads();

    int wv = threadIdx.x >> 6, l = threadIdx.x & 63;
    int r15 = l & 15, kg = l >> 4;
    int row0 = blockIdx.x * 128 + wv * 32;

    short8 a[2][4];
    #pragma unroll
    for (int rt = 0; rt < 2; ++rt) {
        #pragma unroll
        for (int kk = 0; kk < 4; ++kk) {
            int row = row0 + rt * 16 + r15;
            row = min(row, nrows - 1);
            int off = kk * 32 + kg * 8;
            if (AFP32) {
                const float* A = (const float*)Av;
                float4 p = *(const float4*)(A + (size_t)row * D + off);
                float4 q = *(const float4*)(A + (size_t)row * D + off + 4);
                short8 v;
                v[0] = (short)f2bf(p.x); v[1] = (short)f2bf(p.y);
                v[2] = (short)f2bf(p.z); v[3] = (short)f2bf(p.w);
                v[4] = (short)f2bf(q.x); v[5] = (short)f2bf(q.y);
                v[6] = (short)f2bf(q.z); v[7] = (short)f2bf(q.w);
                a[rt][kk] = v;
            } else {
                const unsigned short* A = (const unsigned short*)Av;
                a[rt][kk] = *(const short8*)(A + (size_t)row * D + off);
            }
        }
    }

    f32x4 accY[2][8] = {};
    f32x4 accZ[2][8] = {};
    #pragma unroll
    for (int ct = 0; ct < 8; ++ct) {
        #pragma unroll
        for (int kk = 0; kk < 4; ++kk) {
            short8 bL = sW[(ct * 4 + kk) * 64 + l];
            short8 bR = sW[2048 + (ct * 4 + kk) * 64 + l];
            accY[0][ct] = __builtin_amdgcn_mfma_f32_16x16x32_bf16(a[0][kk], bL, accY[0][ct], 0, 0, 0);
            accY[1][ct] = __builtin_amdgcn_mfma_f32_16x16x32_bf16(a[1][kk], bL, accY[1][ct], 0, 0, 0);
            accZ[0][ct] = __builtin_amdgcn_mfma_f32_16x16x32_bf16(a[0][kk], bR, accZ[0][ct], 0, 0, 0);
            accZ[1][ct] = __builtin_amdgcn_mfma_f32_16x16x32_bf16(a[1][kk], bR, accZ[1][ct], 0, 0, 0);
        }
    }

    // C/D: col = ct*16+(lane&15), row = rt*16+(lane>>4)*4+i
    #pragma unroll
    for (int rt = 0; rt < 2; ++rt) {
        #pragma unroll
        for (int ct = 0; ct < 8; ++ct) {
            #pragma unroll
            for (int i = 0; i < 4; ++i) {
                int row = row0 + rt * 16 + kg * 4 + i;
                if (row < nrows) {
                    int col = ct * 16 + r15;
                    Yf[(size_t)row * D + col] = f2fp8(accY[rt][ct][i]);
                    Zb[(size_t)row * D + col] = f2bf(accZ[rt][ct][i]);
                }
            }
        }
    }
}

// ---------------- mean-aggregate (fp8, R14 form + latency-chain cuts) -----------
// R15/R17/R18 lessons: masks and extra VALU lose; only latency-chain removal is
// left. Two cuts vs R18: (1) Zb epilogue load HOISTED to node start (depends
// only on node -> overlaps gather+butterfly; removes one serial round trip);
// (2) 4-deep main loop (16 edges = one avg node issued in a single batch ->
// one latency exposure per node instead of two). Tails: 2-deep then 1-deep.

template<int RELU, int OUTBF16>
__global__ __launch_bounds__(256) void agg_ep_kernel(const unsigned char* __restrict__ Yf,
        const unsigned short* __restrict__ Zb, const float* __restrict__ bias,
        const int* __restrict__ rowptr, const int* __restrict__ csr,
        void* __restrict__ outp) {
    int lane = threadIdx.x & 63;
    int sub = lane >> 4;
    int m = lane & 15;
    int wv = (blockIdx.x << 2) + (threadIdx.x >> 6);
    int nw = gridDim.x << 2;
    float bb[8];
    #pragma unroll
    for (int e = 0; e < 8; ++e) bb[e] = bias[m * 8 + e];

    for (int node = wv; node < NN; node += nw) {
        int beg = rowptr[node], end = rowptr[node + 1];
        uint4 uz = *(const uint4*)(Zb + (size_t)node * D + m * 8);   // hoisted epilogue load
        f32x2 acc[4] = {};
        int j = beg + sub;
        // 4-deep: 16 edges/iter, all loads issued before any use
        for (; j + 12 < end; j += 16) {
            int s0 = csr[j], s1 = csr[j + 4], s2 = csr[j + 8], s3 = csr[j + 12];
            uint2 u0 = *(const uint2*)(Yf + (size_t)s0 * D + m * 8);
            uint2 u1 = *(const uint2*)(Yf + (size_t)s1 * D + m * 8);
            uint2 u2 = *(const uint2*)(Yf + (size_t)s2 * D + m * 8);
            uint2 u3 = *(const uint2*)(Yf + (size_t)s3 * D + m * 8);
#ifdef HW_FP8
            acc[0] += (__builtin_amdgcn_cvt_pk_f32_fp8(u0.x, false) + __builtin_amdgcn_cvt_pk_f32_fp8(u1.x, false))
                    + (__builtin_amdgcn_cvt_pk_f32_fp8(u2.x, false) + __builtin_amdgcn_cvt_pk_f32_fp8(u3.x, false));
            acc[1] += (__builtin_amdgcn_cvt_pk_f32_fp8(u0.x, true)  + __builtin_amdgcn_cvt_pk_f32_fp8(u1.x, true))
                    + (__builtin_amdgcn_cvt_pk_f32_fp8(u2.x, true)  + __builtin_amdgcn_cvt_pk_f32_fp8(u3.x, true));
            acc[2] += (__builtin_amdgcn_cvt_pk_f32_fp8(u0.y, false) + __builtin_amdgcn_cvt_pk_f32_fp8(u1.y, false))
                    + (__builtin_amdgcn_cvt_pk_f32_fp8(u2.y, false) + __builtin_amdgcn_cvt_pk_f32_fp8(u3.y, false));
            acc[3] += (__builtin_amdgcn_cvt_pk_f32_fp8(u0.y, true)  + __builtin_amdgcn_cvt_pk_f32_fp8(u1.y, true))
                    + (__builtin_amdgcn_cvt_pk_f32_fp8(u2.y, true)  + __builtin_amdgcn_cvt_pk_f32_fp8(u3.y, true));
#else
            #pragma unroll
            for (int e = 0; e < 2; ++e) {
                acc[0][e] += fp8_to_f32((u0.x >> (8 * e)) & 0xff) + fp8_to_f32((u1.x >> (8 * e)) & 0xff)
                           + fp8_to_f32((u2.x >> (8 * e)) & 0xff) + fp8_to_f32((u3.x >> (8 * e)) & 0xff);
                acc[1][e] += fp8_to_f32((u0.x >> (8 * (e + 2))) & 0xff) + fp8_to_f32((u1.x >> (8 * (e + 2))) & 0xff)
                           + fp8_to_f32((u2.x >> (8 * (e + 2))) & 0xff) + fp8_to_f32((u3.x >> (8 * (e + 2))) & 0xff);
                acc[2][e] += fp8_to_f32((u0.y >> (8 * e)) & 0xff) + fp8_to_f32((u1.y >> (8 * e)) & 0xff)
                           + fp8_to_f32((u2.y >> (8 * e)) & 0xff) + fp8_to_f32((u3.y >> (8 * e)) & 0xff);
                acc[3][e] += fp8_to_f32((u0.y >> (8 * (e + 2))) & 0xff) + fp8_to_f32((u1.y >> (8 * (e + 2))) & 0xff)
                           + fp8_to_f32((u2.y >> (8 * (e + 2))) & 0xff) + fp8_to_f32((u3.y >> (8 * (e + 2))) & 0xff);
            }
#endif
        }
        // 2-deep tail
        for (; j + 4 < end; j += 8) {
            int sa = csr[j];
            int sb = csr[j + 4];
            uint2 ua = *(const uint2*)(Yf + (size_t)sa * D + m * 8);
            uint2 ub = *(const uint2*)(Yf + (size_t)sb * D + m * 8);
#ifdef HW_FP8
            acc[0] += __builtin_amdgcn_cvt_pk_f32_fp8(ua.x, false) + __builtin_amdgcn_cvt_pk_f32_fp8(ub.x, false);
            acc[1] += __builtin_amdgcn_cvt_pk_f32_fp8(ua.x, true)  + __builtin_amdgcn_cvt_pk_f32_fp8(ub.x, true);
            acc[2] += __builtin_amdgcn_cvt_pk_f32_fp8(ua.y, false) + __builtin_amdgcn_cvt_pk_f32_fp8(ub.y, false);
            acc[3] += __builtin_amdgcn_cvt_pk_f32_fp8(ua.y, true)  + __builtin_amdgcn_cvt_pk_f32_fp8(ub.y, true);
#else
            #pragma unroll
            for (int e = 0; e < 2; ++e) {
                acc[0][e] += fp8_to_f32((ua.x >> (8 * e)) & 0xff) + fp8_to_f32((ub.x >> (8 * e)) & 0xff);
                acc[1][e] += fp8_to_f32((ua.x >> (8 * (e + 2))) & 0xff) + fp8_to_f32((ub.x >> (8 * (e + 2))) & 0xff);
                acc[2][e] += fp8_to_f32((ua.y >> (8 * e)) & 0xff) + fp8_to_f32((ub.y >> (8 * e)) & 0xff);
                acc[3][e] += fp8_to_f32((ua.y >> (8 * (e + 2))) & 0xff) + fp8_to_f32((ub.y >> (8 * (e + 2))) & 0xff);
            }
#endif
        }
        // 1-deep tail
        if (j < end) {
            int sa = csr[j];
            uint2 ua = *(const uint2*)(Yf + (size_t)sa * D + m * 8);
#ifdef HW_FP8
            acc[0] += __builtin_amdgcn_cvt_pk_f32_fp8(ua.x, false);
            acc[1] += __builtin_amdgcn_cvt_pk_f32_fp8(ua.x, true);
            acc[2] += __builtin_amdgcn_cvt_pk_f32_fp8(ua.y, false);
            acc[3] += __builtin_amdgcn_cvt_pk_f32_fp8(ua.y, true);
#else
            #pragma unroll
            for (int e = 0; e < 2; ++e) {
                acc[0][e] += fp8_to_f32((ua.x >> (8 * e)) & 0xff);
                acc[1][e] += fp8_to_f32((ua.x >> (8 * (e + 2))) & 0xff);
                acc[2][e] += fp8_to_f32((ua.y >> (8 * e)) & 0xff);
                acc[3][e] += fp8_to_f32((ua.y >> (8 * (e + 2))) & 0xff);
            }
#endif
        }
        float a8[8];
        #pragma unroll
        for (int i = 0; i < 4; ++i) { a8[2 * i] = acc[i][0]; a8[2 * i + 1] = acc[i][1]; }
        #pragma unroll
        for (int e = 0; e < 8; ++e) {
            a8[e] += __shfl_xor(a8[e], 16, 64);
            a8[e] += __shfl_xor(a8[e], 32, 64);
        }
        if (sub == 0) {
            float inv = (end > beg) ? 1.f / (float)(end - beg) : 0.f;
            float v[8];
            v[0] = a8[0] * inv + bb[0] + bflo(uz.x);
            v[1] = a8[1] * inv + bb[1] + bfhi(uz.x);
            v[2] = a8[2] * inv + bb[2] + bflo(uz.y);
            v[3] = a8[3] * inv + bb[3] + bfhi(uz.y);
            v[4] = a8[4] * inv + bb[4] + bflo(uz.z);
            v[5] = a8[5] * inv + bb[5] + bfhi(uz.z);
            v[6] = a8[6] * inv + bb[6] + bflo(uz.w);
            v[7] = a8[7] * inv + bb[7] + bfhi(uz.w);
            if (RELU) {
                #pragma unroll
                for (int e = 0; e < 8; ++e) v[e] = fmaxf(v[e], 0.f);
            }
            if (OUTBF16) {
                uint4 o;
                o.x = (unsigned)f2bf(v[0]) | ((unsigned)f2bf(v[1]) << 16);
                o.y = (unsigned)f2bf(v[2]) | ((unsigned)f2bf(v[3]) << 16);
                o.z = (unsigned)f2bf(v[4]) | ((unsigned)f2bf(v[5]) << 16);
                o.w = (unsigned)f2bf(v[6]) | ((unsigned)f2bf(v[7]) << 16);
                *(uint4*)((unsigned short*)outp + (size_t)node * D + m * 8) = o;
            } else {
                float* op = (float*)outp + (size_t)node * D + m * 8;
                f32x4 o1 = {v[0], v[1], v[2], v[3]};
                f32x4 o2 = {v[4], v[5], v[6], v[7]};
                __builtin_nontemporal_store(o1, (f32x4*)op);        // out never re-read
                __builtin_nontemporal_store(o2, (f32x4*)(op + 4));
            }
        }
    }
}

// ---------------- launch ----------------

extern "C" void kernel_launch(void* const* d_in, const int* in_sizes, int n_in,
                              void* d_out, int out_size, void* d_ws, size_t ws_size,
                              hipStream_t stream) {
    const float* x   = (const float*)d_in[0];
    const int*   ei  = (const int*)d_in[1];
    const float* W1l = (const float*)d_in[2];
    const float* b1  = (const float*)d_in[3];
    const float* W1r = (const float*)d_in[4];
    const float* W2l = (const float*)d_in[5];
    const float* b2  = (const float*)d_in[6];
    const float* W2r = (const float*)d_in[7];
    float* out = (float*)d_out;

    const int N = NN, E = NE;
    const int* src = ei;
    const int* dst = ei + E;

    char* ws = (char*)d_ws;
    size_t off = 0;
    auto alloc = [&](size_t bytes) -> void* {
        void* p = ws + off;
        off += (bytes + 255) & ~(size_t)255;
        return p;
    };
    int* rowptr  = (int*)alloc((size_t)(N + 1) * 4);
    int* csr     = (int*)alloc((size_t)E * 4);
    int* bh      = (int*)alloc((size_t)FLAT * 4);
    int* bases   = (int*)alloc((size_t)FLAT * 4);
    int* segTot  = (int*)alloc(256 * 4);
    int* segBase = (int*)alloc((size_t)(NSEG + 1) * 4);
    unsigned* bucket = (unsigned*)alloc((size_t)E * 4);
    unsigned short* hb  = (unsigned short*)alloc((size_t)N * D * 2);
    unsigned char*  Yf  = (unsigned char*)alloc((size_t)N * D);       // fp8 e4m3
    unsigned short* Zb  = (unsigned short*)alloc((size_t)N * D * 2);
    unsigned short* wf  = (unsigned short*)alloc((size_t)4 * 16384 * 2);

    // CSR build (atomic-free counting sort, two-level); histA also frag-packs W
    histA_kernel<<<GRID_A, 256, 0, stream>>>(dst, bh, W1l, W1r, W2l, W2r, wf);
    segscan_kernel<<<NSEG, 256, 0, stream>>>(bh, bases, segTot);
    segbase_kernel<<<1, 256, 0, stream>>>(segTot, segBase);
    scatA_kernel<<<GRID_A, 256, 0, stream>>>(src, dst, bases, segBase, bucket);
    buildB_kernel<<<NSEG, 256, 0, stream>>>(bucket, segBase, rowptr, csr);

    unsigned short* wf1l = wf;
    unsigned short* wf1r = wf + 16384;
    unsigned short* wf2l = wf + 2 * 16384;
    unsigned short* wf2r = wf + 3 * 16384;

    int gblocks = (N + 127) / 128;

    // layer 1 (fp32 x consumed directly by gemm)
    gemm_kernel<1><<<gblocks, 256, 0, stream>>>(x, wf1l, wf1r, Yf, Zb, N);
    agg_ep_kernel<1, 1><<<2048, 256, 0, stream>>>(Yf, Zb, b1, rowptr, csr, hb);

    // layer 2
    gemm_kernel<0><<<gblocks, 256, 0, stream>>>(hb, wf2l, wf2r, Yf, Zb, N);
    agg_ep_kernel<0, 0><<<2048, 256, 0, stream>>>(Yf, Zb, b2, rowptr, csr, out);
}

// Round 20
// 116.507 us; speedup vs baseline: 1.1180x; 1.1180x over previous
//
#include <hip/hip_runtime.h>

#define NN 50000
#define NE 800000
#define D 128
#define SEGBITS 8
#define SEGSZ 256
#define NSEG 196         // ceil(50000/256)
#define GRID_A 1024
#define EPB ((NE + GRID_A - 1) / GRID_A)   // 782
#define FLAT (NSEG * GRID_A)               // 200704

typedef __attribute__((ext_vector_type(8))) short short8;
typedef __attribute__((ext_vector_type(4))) float f32x4;
typedef __attribute__((ext_vector_type(2))) float f32x2;

__device__ inline unsigned short f2bf(float f) {
    unsigned u = __builtin_bit_cast(unsigned, f);
    unsigned r = (u + 0x7fffu + ((u >> 16) & 1u)) >> 16;
    return (unsigned short)r;
}
__device__ inline float bflo(unsigned u) { return __builtin_bit_cast(float, u << 16); }
__device__ inline float bfhi(unsigned u) { return __builtin_bit_cast(float, u & 0xffff0000u); }

// ---- fp8 e4m3 encode/decode (hardware cvt on gfx950; software fallback) ----
#if __has_builtin(__builtin_amdgcn_cvt_pk_f32_fp8) && __has_builtin(__builtin_amdgcn_cvt_pk_fp8_f32)
#define HW_FP8 1
#endif

__device__ inline unsigned char f2fp8(float f) {
#ifdef HW_FP8
    int r = __builtin_amdgcn_cvt_pk_fp8_f32(f, f, 0, false);
    return (unsigned char)(r & 0xff);
#else
    float a = fabsf(f);
    unsigned s = (__builtin_bit_cast(unsigned, f) >> 31) << 7;
    a = fminf(a, 448.f);
    if (a < 0.015625f) {                       // subnormal: m * 2^-9
        unsigned m = (unsigned)(a * 512.f + 0.5f);
        return (unsigned char)(s | m);
    }
    unsigned u = __builtin_bit_cast(unsigned, a);
    u += 0x0FFFFF + ((u >> 20) & 1);           // RTN-even to 3 mantissa bits
    int e8 = (int)(u >> 23) - 127 + 7;
    unsigned m = (u >> 20) & 7;
    unsigned code = (unsigned)(e8 << 3) | m;
    if (code > 0x7E) code = 0x7E;              // saturate to 448
    return (unsigned char)(s | code);
#endif
}

#ifndef HW_FP8
__device__ inline float fp8_to_f32(unsigned char c) {
    unsigned s = (c >> 7) & 1u, e = (c >> 3) & 15u, m = c & 7u;
    float v = (e == 0) ? (float)m * 0.001953125f
                       : __builtin_bit_cast(float, ((e + 120u) << 23) | (m << 20));
    return s ? -v : v;
}
#endif

// ---------------- CSR build: atomic-free two-level counting sort ----------------

// A1: per-block coarse histogram (196 segments); blocks 0..31 also frag-pack W
__global__ __launch_bounds__(256) void histA_kernel(const int* __restrict__ dst,
        int* __restrict__ bh,
        const float* __restrict__ W0, const float* __restrict__ W1,
        const float* __restrict__ W2, const float* __restrict__ W3,
        unsigned short* __restrict__ wf) {
    __shared__ int h[NSEG];
    int t = threadIdx.x;
    int b = blockIdx.x;
    if (t < NSEG) h[t] = 0;
    __syncthreads();
    int beg = b * EPB;
    int end = min(beg + EPB, NE);
    for (int e = beg + t; e < end; e += 256) atomicAdd(&h[dst[e] >> SEGBITS], 1);
    __syncthreads();
    if (t < NSEG) bh[t * GRID_A + b] = h[t];
    if (b < 32) {   // prep_w: frag f=ct*4+kk, lane l: col=ct*16+(l&15), k=kk*32+(l>>4)*8+e
        int tg = b * 256 + t;
        int w = tg >> 11, rem = tg & 2047;
        int f = rem >> 6, l = rem & 63;
        int ct = f >> 2, kk = f & 3;
        int col = ct * 16 + (l & 15);
        int k0 = kk * 32 + (l >> 4) * 8;
        const float* W = (w == 0) ? W0 : (w == 1) ? W1 : (w == 2) ? W2 : W3;
        unsigned short* o = wf + (size_t)w * 16384 + ((size_t)f * 64 + l) * 8;
        #pragma unroll
        for (int e = 0; e < 8; ++e) o[e] = f2bf(W[(k0 + e) * D + col]);
    }
}

// A2a: per-segment scan of its 1024 per-block counts -> bases + segment total
__global__ __launch_bounds__(256) void segscan_kernel(const int* __restrict__ bh,
        int* __restrict__ bases, int* __restrict__ segTot) {
    __shared__ int s[256];
    int sg = blockIdx.x, t = threadIdx.x;
    const int* p = bh + (size_t)sg * GRID_A;
    int v0 = p[t * 4], v1 = p[t * 4 + 1], v2 = p[t * 4 + 2], v3 = p[t * 4 + 3];
    int sum = v0 + v1 + v2 + v3;
    s[t] = sum;
    __syncthreads();
    #pragma unroll
    for (int off = 1; off < 256; off <<= 1) {
        int u = (t >= off) ? s[t - off] : 0;
        __syncthreads();
        s[t] += u;
        __syncthreads();
    }
    int run = s[t] - sum;
    int* q = bases + (size_t)sg * GRID_A;
    q[t * 4] = run; run += v0;
    q[t * 4 + 1] = run; run += v1;
    q[t * 4 + 2] = run; run += v2;
    q[t * 4 + 3] = run;
    if (t == 255) segTot[sg] = s[255];
}

// A2b: exclusive scan of 196 segment totals -> segBase
__global__ __launch_bounds__(256) void segbase_kernel(const int* __restrict__ segTot,
        int* __restrict__ segBase) {
    __shared__ int s[256];
    int t = threadIdx.x;
    int v = (t < NSEG) ? segTot[t] : 0;
    s[t] = v;
    __syncthreads();
    #pragma unroll
    for (int off = 1; off < 256; off <<= 1) {
        int u = (t >= off) ? s[t - off] : 0;
        __syncthreads();
        s[t] += u;
        __syncthreads();
    }
    if (t < NSEG) segBase[t] = s[t] - v;
    if (t == 0) segBase[NSEG] = NE;
}

// A3: scatter edges into segment buckets, packed (dst_local<<24 | src)
__global__ __launch_bounds__(256) void scatA_kernel(const int* __restrict__ src,
        const int* __restrict__ dst, const int* __restrict__ bases,
        const int* __restrict__ segBase, unsigned* __restrict__ bucket) {
    __shared__ int cur[NSEG];
    int t = threadIdx.x;
    if (t < NSEG) cur[t] = segBase[t] + bases[t * GRID_A + blockIdx.x];
    __syncthreads();
    int beg = blockIdx.x * EPB;
    int end = min(beg + EPB, NE);
    for (int e = beg + t; e < end; e += 256) {
        int d = dst[e];
        int sg = d >> SEGBITS;
        int p = atomicAdd(&cur[sg], 1);          // LDS atomic
        bucket[p] = ((unsigned)(d & (SEGSZ - 1)) << 24) | (unsigned)src[e];
    }
}

// B: per-segment fine histogram (1 bin/thread) + in-LDS scan -> rowptr + csr
__global__ __launch_bounds__(256) void buildB_kernel(const unsigned* __restrict__ bucket,
        const int* __restrict__ segBase, int* __restrict__ rowptr, int* __restrict__ csr) {
    __shared__ int h[SEGSZ];    // 1 KB, bin t owned by thread t
    __shared__ int s[SEGSZ];
    int sg = blockIdx.x;
    int t = threadIdx.x;
    int beg = segBase[sg], end = segBase[sg + 1];
    h[t] = 0;
    __syncthreads();
    for (int i = beg + t; i < end; i += 256) atomicAdd(&h[bucket[i] >> 24], 1);  // LDS
    __syncthreads();
    int v = h[t];
    s[t] = v;
    __syncthreads();
    #pragma unroll
    for (int off = 1; off < 256; off <<= 1) {
        int u = (t >= off) ? s[t - off] : 0;
        __syncthreads();
        s[t] += u;
        __syncthreads();
    }
    int excl = beg + s[t] - v;
    int n = sg * SEGSZ + t;
    if (n <= NN) rowptr[n] = excl;      // covers rowptr[NN] = NE (node 50000 -> sg 195, t 80)
    h[t] = excl;                        // becomes placement cursor
    __syncthreads();
    for (int i = beg + t; i < end; i += 256) {
        unsigned u = bucket[i];
        int p = atomicAdd(&h[u >> 24], 1);       // LDS
        csr[p] = (int)(u & 0xFFFFFFu);
    }
}

// ---------------- dual-output bf16 MFMA GEMM: Y(fp8) = A@Wl, Z(bf16) = A@Wr ----
// LDS-staged W (64 KB) amortizes W-frag L2 latency (R10 vs R11: 132.6 vs 138.6).
// launch_bounds (256,2): 2 blocks/CU (2x64KB LDS fits in 160KB).
// AFP32: A is fp32 row-major (converted to bf16 frags in-register)

template<int AFP32>
__global__ __launch_bounds__(256, 2) void gemm_kernel(const void* __restrict__ Av,
        const unsigned short* __restrict__ WfL, const unsigned short* __restrict__ WfR,
        unsigned char* __restrict__ Yf, unsigned short* __restrict__ Zb, int nrows) {
    __shared__ short8 sW[4096];   // Wl frags | Wr frags (64 KB)

    for (int i = threadIdx.x; i < 2048; i += 256) {
        sW[i]        = ((const short8*)WfL)[i];
        sW[i + 2048] = ((const short8*)WfR)[i];
    }
    __syncthreads();

    int wv = threadIdx.x >> 6, l = threadIdx.x & 63;
    int r15 = l & 15, kg = l >> 4;
    int row0 = blockIdx.x * 128 + wv * 32;

    short8 a[2][4];
    #pragma unroll
    for (int rt = 0; rt < 2; ++rt) {
        #pragma unroll
        for (int kk = 0; kk < 4; ++kk) {
            int row = row0 + rt * 16 + r15;
            row = min(row, nrows - 1);
            int off = kk * 32 + kg * 8;
            if (AFP32) {
                const float* A = (const float*)Av;
                float4 p = *(const float4*)(A + (size_t)row * D + off);
                float4 q = *(const float4*)(A + (size_t)row * D + off + 4);
                short8 v;
                v[0] = (short)f2bf(p.x); v[1] = (short)f2bf(p.y);
                v[2] = (short)f2bf(p.z); v[3] = (short)f2bf(p.w);
                v[4] = (short)f2bf(q.x); v[5] = (short)f2bf(q.y);
                v[6] = (short)f2bf(q.z); v[7] = (short)f2bf(q.w);
                a[rt][kk] = v;
            } else {
                const unsigned short* A = (const unsigned short*)Av;
                a[rt][kk] = *(const short8*)(A + (size_t)row * D + off);
            }
        }
    }

    f32x4 accY[2][8] = {};
    f32x4 accZ[2][8] = {};
    #pragma unroll
    for (int ct = 0; ct < 8; ++ct) {
        #pragma unroll
        for (int kk = 0; kk < 4; ++kk) {
            short8 bL = sW[(ct * 4 + kk) * 64 + l];
            short8 bR = sW[2048 + (ct * 4 + kk) * 64 + l];
            accY[0][ct] = __builtin_amdgcn_mfma_f32_16x16x32_bf16(a[0][kk], bL, accY[0][ct], 0, 0, 0);
            accY[1][ct] = __builtin_amdgcn_mfma_f32_16x16x32_bf16(a[1][kk], bL, accY[1][ct], 0, 0, 0);
            accZ[0][ct] = __builtin_amdgcn_mfma_f32_16x16x32_bf16(a[0][kk], bR, accZ[0][ct], 0, 0, 0);
            accZ[1][ct] = __builtin_amdgcn_mfma_f32_16x16x32_bf16(a[1][kk], bR, accZ[1][ct], 0, 0, 0);
        }
    }

    // C/D: col = ct*16+(lane&15), row = rt*16+(lane>>4)*4+i
    #pragma unroll
    for (int rt = 0; rt < 2; ++rt) {
        #pragma unroll
        for (int ct = 0; ct < 8; ++ct) {
            #pragma unroll
            for (int i = 0; i < 4; ++i) {
                int row = row0 + rt * 16 + kg * 4 + i;
                if (row < nrows) {
                    int col = ct * 16 + r15;
                    Yf[(size_t)row * D + col] = f2fp8(accY[rt][ct][i]);
                    Zb[(size_t)row * D + col] = f2bf(accZ[rt][ct][i]);
                }
            }
        }
    }
}

// ---------------- mean-aggregate (fp8, R14 form, packed f32 accumulate) ---------
// Final form after R15-R19 ablations: single node per wave, unconditional
// 2-deep unrolled loads, Zb load inside sub==0 (16 lanes only), pk_add f32
// accumulate. Every structural perturbation tried (pair-interleave, masked
// loads, 4-deep unroll, hoisted Zb) lost or was neutral -- this gather runs at
// ~4.8 TB/s effective random-128B throughput, near the fabric/L3 ceiling.

template<int RELU, int OUTBF16>
__global__ __launch_bounds__(256) void agg_ep_kernel(const unsigned char* __restrict__ Yf,
        const unsigned short* __restrict__ Zb, const float* __restrict__ bias,
        const int* __restrict__ rowptr, const int* __restrict__ csr,
        void* __restrict__ outp) {
    int lane = threadIdx.x & 63;
    int sub = lane >> 4;
    int m = lane & 15;
    int wv = (blockIdx.x << 2) + (threadIdx.x >> 6);
    int nw = gridDim.x << 2;
    float bb[8];
    #pragma unroll
    for (int e = 0; e < 8; ++e) bb[e] = bias[m * 8 + e];

    for (int node = wv; node < NN; node += nw) {
        int beg = rowptr[node], end = rowptr[node + 1];
        f32x2 acc[4] = {};
        int j = beg + sub;
        for (; j + 4 < end; j += 8) {
            int sa = csr[j];
            int sb = csr[j + 4];
            uint2 ua = *(const uint2*)(Yf + (size_t)sa * D + m * 8);
            uint2 ub = *(const uint2*)(Yf + (size_t)sb * D + m * 8);
#ifdef HW_FP8
            f32x2 p0 = __builtin_amdgcn_cvt_pk_f32_fp8(ua.x, false);
            f32x2 p1 = __builtin_amdgcn_cvt_pk_f32_fp8(ua.x, true);
            f32x2 p2 = __builtin_amdgcn_cvt_pk_f32_fp8(ua.y, false);
            f32x2 p3 = __builtin_amdgcn_cvt_pk_f32_fp8(ua.y, true);
            f32x2 q0 = __builtin_amdgcn_cvt_pk_f32_fp8(ub.x, false);
            f32x2 q1 = __builtin_amdgcn_cvt_pk_f32_fp8(ub.x, true);
            f32x2 q2 = __builtin_amdgcn_cvt_pk_f32_fp8(ub.y, false);
            f32x2 q3 = __builtin_amdgcn_cvt_pk_f32_fp8(ub.y, true);
            acc[0] += p0 + q0;       // v_pk_add_f32 x2
            acc[1] += p1 + q1;
            acc[2] += p2 + q2;
            acc[3] += p3 + q3;
#else
            #pragma unroll
            for (int e = 0; e < 2; ++e) {
                acc[0][e] += fp8_to_f32((ua.x >> (8 * e)) & 0xff) + fp8_to_f32((ub.x >> (8 * e)) & 0xff);
                acc[1][e] += fp8_to_f32((ua.x >> (8 * (e + 2))) & 0xff) + fp8_to_f32((ub.x >> (8 * (e + 2))) & 0xff);
                acc[2][e] += fp8_to_f32((ua.y >> (8 * e)) & 0xff) + fp8_to_f32((ub.y >> (8 * e)) & 0xff);
                acc[3][e] += fp8_to_f32((ua.y >> (8 * (e + 2))) & 0xff) + fp8_to_f32((ub.y >> (8 * (e + 2))) & 0xff);
            }
#endif
        }
        if (j < end) {
            int sa = csr[j];
            uint2 ua = *(const uint2*)(Yf + (size_t)sa * D + m * 8);
#ifdef HW_FP8
            acc[0] += __builtin_amdgcn_cvt_pk_f32_fp8(ua.x, false);
            acc[1] += __builtin_amdgcn_cvt_pk_f32_fp8(ua.x, true);
            acc[2] += __builtin_amdgcn_cvt_pk_f32_fp8(ua.y, false);
            acc[3] += __builtin_amdgcn_cvt_pk_f32_fp8(ua.y, true);
#else
            #pragma unroll
            for (int e = 0; e < 2; ++e) {
                acc[0][e] += fp8_to_f32((ua.x >> (8 * e)) & 0xff);
                acc[1][e] += fp8_to_f32((ua.x >> (8 * (e + 2))) & 0xff);
                acc[2][e] += fp8_to_f32((ua.y >> (8 * e)) & 0xff);
                acc[3][e] += fp8_to_f32((ua.y >> (8 * (e + 2))) & 0xff);
            }
#endif
        }
        float a8[8];
        #pragma unroll
        for (int i = 0; i < 4; ++i) { a8[2 * i] = acc[i][0]; a8[2 * i + 1] = acc[i][1]; }
        #pragma unroll
        for (int e = 0; e < 8; ++e) {
            a8[e] += __shfl_xor(a8[e], 16, 64);
            a8[e] += __shfl_xor(a8[e], 32, 64);
        }
        if (sub == 0) {
            float inv = (end > beg) ? 1.f / (float)(end - beg) : 0.f;
            uint4 uz = *(const uint4*)(Zb + (size_t)node * D + m * 8);
            float v[8];
            v[0] = a8[0] * inv + bb[0] + bflo(uz.x);
            v[1] = a8[1] * inv + bb[1] + bfhi(uz.x);
            v[2] = a8[2] * inv + bb[2] + bflo(uz.y);
            v[3] = a8[3] * inv + bb[3] + bfhi(uz.y);
            v[4] = a8[4] * inv + bb[4] + bflo(uz.z);
            v[5] = a8[5] * inv + bb[5] + bfhi(uz.z);
            v[6] = a8[6] * inv + bb[6] + bflo(uz.w);
            v[7] = a8[7] * inv + bb[7] + bfhi(uz.w);
            if (RELU) {
                #pragma unroll
                for (int e = 0; e < 8; ++e) v[e] = fmaxf(v[e], 0.f);
            }
            if (OUTBF16) {
                uint4 o;
                o.x = (unsigned)f2bf(v[0]) | ((unsigned)f2bf(v[1]) << 16);
                o.y = (unsigned)f2bf(v[2]) | ((unsigned)f2bf(v[3]) << 16);
                o.z = (unsigned)f2bf(v[4]) | ((unsigned)f2bf(v[5]) << 16);
                o.w = (unsigned)f2bf(v[6]) | ((unsigned)f2bf(v[7]) << 16);
                *(uint4*)((unsigned short*)outp + (size_t)node * D + m * 8) = o;
            } else {
                float* op = (float*)outp + (size_t)node * D + m * 8;
                f32x4 o1 = {v[0], v[1], v[2], v[3]};
                f32x4 o2 = {v[4], v[5], v[6], v[7]};
                __builtin_nontemporal_store(o1, (f32x4*)op);        // out never re-read
                __builtin_nontemporal_store(o2, (f32x4*)(op + 4));
            }
        }
    }
}

// ---------------- launch ----------------

extern "C" void kernel_launch(void* const* d_in, const int* in_sizes, int n_in,
                              void* d_out, int out_size, void* d_ws, size_t ws_size,
                              hipStream_t stream) {
    const float* x   = (const float*)d_in[0];
    const int*   ei  = (const int*)d_in[1];
    const float* W1l = (const float*)d_in[2];
    const float* b1  = (const float*)d_in[3];
    const float* W1r = (const float*)d_in[4];
    const float* W2l = (const float*)d_in[5];
    const float* b2  = (const float*)d_in[6];
    const float* W2r = (const float*)d_in[7];
    float* out = (float*)d_out;

    const int N = NN, E = NE;
    const int* src = ei;
    const int* dst = ei + E;

    char* ws = (char*)d_ws;
    size_t off = 0;
    auto alloc = [&](size_t bytes) -> void* {
        void* p = ws + off;
        off += (bytes + 255) & ~(size_t)255;
        return p;
    };
    int* rowptr  = (int*)alloc((size_t)(N + 1) * 4);
    int* csr     = (int*)alloc((size_t)E * 4);
    int* bh      = (int*)alloc((size_t)FLAT * 4);
    int* bases   = (int*)alloc((size_t)FLAT * 4);
    int* segTot  = (int*)alloc(256 * 4);
    int* segBase = (int*)alloc((size_t)(NSEG + 1) * 4);
    unsigned* bucket = (unsigned*)alloc((size_t)E * 4);
    unsigned short* hb  = (unsigned short*)alloc((size_t)N * D * 2);
    unsigned char*  Yf  = (unsigned char*)alloc((size_t)N * D);       // fp8 e4m3
    unsigned short* Zb  = (unsigned short*)alloc((size_t)N * D * 2);
    unsigned short* wf  = (unsigned short*)alloc((size_t)4 * 16384 * 2);

    // CSR build (atomic-free counting sort, two-level); histA also frag-packs W
    histA_kernel<<<GRID_A, 256, 0, stream>>>(dst, bh, W1l, W1r, W2l, W2r, wf);
    segscan_kernel<<<NSEG, 256, 0, stream>>>(bh, bases, segTot);
    segbase_kernel<<<1, 256, 0, stream>>>(segTot, segBase);
    scatA_kernel<<<GRID_A, 256, 0, stream>>>(src, dst, bases, segBase, bucket);
    buildB_kernel<<<NSEG, 256, 0, stream>>>(bucket, segBase, rowptr, csr);

    unsigned short* wf1l = wf;
    unsigned short* wf1r = wf + 16384;
    unsigned short* wf2l = wf + 2 * 16384;
    unsigned short* wf2r = wf + 3 * 16384;

    int gblocks = (N + 127) / 128;

    // layer 1 (fp32 x consumed directly by gemm)
    gemm_kernel<1><<<gblocks, 256, 0, stream>>>(x, wf1l, wf1r, Yf, Zb, N);
    agg_ep_kernel<1, 1><<<2048, 256, 0, stream>>>(Yf, Zb, b1, rowptr, csr, hb);

    // layer 2
    gemm_kernel<0><<<gblocks, 256, 0, stream>>>(hb, wf2l, wf2r, Yf, Zb, N);
    agg_ep_kernel<0, 0><<<2048, 256, 0, stream>>>(Yf, Zb, b2, rowptr, csr, out);
}